// Round 1
// baseline (1900.199 us; speedup 1.0000x reference)
//
#include <hip/hip_runtime.h>

namespace {
constexpr int B  = 64;
constexpr int D  = 128;
constexpr int K1 = 16385;            // K+1
constexpr long long NROWS = 1000000;
constexpr float INV_T = 1.0f / 0.07f;
constexpr int CHUNKS = 64;
constexpr int KPB = (K1 + CHUNKS - 1) / CHUNKS;   // 257 k-values per block

constexpr size_t OUT_V1 = 0;
constexpr size_t OUT_V2 = (size_t)B * K1;                    // 1,048,640
constexpr size_t OUT_M1 = 2 * (size_t)B * K1;                // 2,097,280
constexpr size_t OUT_M2 = OUT_M1 + (size_t)NROWS * D;        // 130,097,280
}

// ---------------------------------------------------------------------------
// Kernel 1: gathered dot products + exp, unnormalized; double block-sums -> ws
// One block = one b, one chunk of k. Each wave handles 2 (b,k) pairs: 32-lane
// half reads one 512B row as float4/lane (fully coalesced), dots against the
// register-resident v-fragment, butterfly-reduces within the half.
// ---------------------------------------------------------------------------
__global__ __launch_bounds__(256) void nce_dots_kernel(
    const float* __restrict__ v1, const float* __restrict__ v2,
    const int* __restrict__ idx,
    const float* __restrict__ mem1, const float* __restrict__ mem2,
    float* __restrict__ out, double* __restrict__ sums)
{
  const int b = blockIdx.x / CHUNKS;
  const int c = blockIdx.x % CHUNKS;
  const int kstart = c * KPB;
  const int kend   = min(kstart + KPB, K1);

  const int tid  = threadIdx.x;
  const int wave = tid >> 6;
  const int lane = tid & 63;
  const int half = lane >> 5;
  const int sub  = lane & 31;

  // b is block-uniform: keep v fragments in registers (no LDS needed)
  const float4 v1f = ((const float4*)(v1 + b * D))[sub];
  const float4 v2f = ((const float4*)(v2 + b * D))[sub];

  double acc1 = 0.0, acc2 = 0.0;

  for (int kbase = kstart; kbase < kend; kbase += 8) {
    const int k = kbase + wave * 2 + half;   // uniform within each 32-lane half
    if (k < kend) {
      const int row = idx[b * K1 + k];
      const float4 m1 = ((const float4*)(mem1 + (size_t)row * D))[sub];
      const float4 m2 = ((const float4*)(mem2 + (size_t)row * D))[sub];
      // out_v2 = exp(<mem1 row, v2>/T), out_v1 = exp(<mem2 row, v1>/T)
      float d2 = m1.x*v2f.x + m1.y*v2f.y + m1.z*v2f.z + m1.w*v2f.w;
      float d1 = m2.x*v1f.x + m2.y*v1f.y + m2.z*v1f.z + m2.w*v1f.w;
      #pragma unroll
      for (int m = 1; m < 32; m <<= 1) {   // stays inside the 32-lane half
        d1 += __shfl_xor(d1, m, 64);
        d2 += __shfl_xor(d2, m, 64);
      }
      if (sub == 0) {
        const float e1 = expf(d1 * INV_T);
        const float e2 = expf(d2 * INV_T);
        out[OUT_V1 + (size_t)b * K1 + k] = e1;
        out[OUT_V2 + (size_t)b * K1 + k] = e2;
        acc1 += (double)e1;
        acc2 += (double)e2;
      }
    }
  }

  // full-wave reduce (only lanes 0/32 carry nonzero)
  #pragma unroll
  for (int m = 1; m < 64; m <<= 1) {
    acc1 += __shfl_xor(acc1, m, 64);
    acc2 += __shfl_xor(acc2, m, 64);
  }

  __shared__ double s1[4], s2[4];
  if (lane == 0) { s1[wave] = acc1; s2[wave] = acc2; }
  __syncthreads();
  if (tid == 0) {
    atomicAdd(&sums[0], s1[0] + s1[1] + s1[2] + s1[3]);
    atomicAdd(&sums[1], s2[0] + s2[1] + s2[2] + s2[3]);
  }
}

// ---------------------------------------------------------------------------
// Kernel 2: streaming copy of both memory banks into the output (float4).
// ---------------------------------------------------------------------------
__global__ __launch_bounds__(256) void copy_mem_kernel(
    const float4* __restrict__ a, float4* __restrict__ oa,
    const float4* __restrict__ b, float4* __restrict__ ob, size_t n4)
{
  size_t i = (size_t)blockIdx.x * blockDim.x + threadIdx.x;
  const size_t stride = (size_t)gridDim.x * blockDim.x;
  for (; i < n4; i += stride) {
    oa[i] = a[i];
    ob[i] = b[i];
  }
}

// ---------------------------------------------------------------------------
// Kernel 3: momentum update + l2 renorm of rows y[b], last-occurrence wins
// (matches scatter "last wins" for duplicate y). One wave per b.
// ---------------------------------------------------------------------------
__global__ __launch_bounds__(64) void update_rows_kernel(
    const float* __restrict__ v1, const float* __restrict__ v2,
    const int* __restrict__ y,
    const float* __restrict__ mem1, const float* __restrict__ mem2,
    float* __restrict__ out)
{
  const int b  = blockIdx.x;
  const int yb = y[b];
  for (int b2 = b + 1; b2 < B; ++b2)
    if (y[b2] == yb) return;                // a later update overwrites us: skip

  const int l = threadIdx.x;                // 0..63, each lane owns d = l, l+64
  const size_t r = (size_t)yb * D;
  float a0 = mem1[r + l]      * 0.5f + v1[b * D + l]      * 0.5f;
  float a1 = mem1[r + l + 64] * 0.5f + v1[b * D + l + 64] * 0.5f;
  float b0 = mem2[r + l]      * 0.5f + v2[b * D + l]      * 0.5f;
  float b1 = mem2[r + l + 64] * 0.5f + v2[b * D + l + 64] * 0.5f;

  float ssa = a0 * a0 + a1 * a1;
  float ssb = b0 * b0 + b1 * b1;
  #pragma unroll
  for (int m = 1; m < 64; m <<= 1) {
    ssa += __shfl_xor(ssa, m, 64);
    ssb += __shfl_xor(ssb, m, 64);
  }
  const float ra = 1.0f / sqrtf(ssa);
  const float rb = 1.0f / sqrtf(ssb);
  out[OUT_M1 + r + l]      = a0 * ra;
  out[OUT_M1 + r + l + 64] = a1 * ra;
  out[OUT_M2 + r + l]      = b0 * rb;
  out[OUT_M2 + r + l + 64] = b1 * rb;
}

// ---------------------------------------------------------------------------
// Kernel 4: divide out_v1/out_v2 by Z1/Z2 (Z = mean * N), computed in double.
// ---------------------------------------------------------------------------
__global__ __launch_bounds__(256) void scale_out_kernel(
    float* __restrict__ out, const double* __restrict__ sums)
{
  const double cnt = (double)((size_t)B * K1);
  const float f1 = (float)(cnt / (sums[0] * (double)NROWS));
  const float f2 = (float)(cnt / (sums[1] * (double)NROWS));
  const size_t bk = (size_t)B * K1;
  const size_t total = 2 * bk;
  size_t i = (size_t)blockIdx.x * blockDim.x + threadIdx.x;
  const size_t stride = (size_t)gridDim.x * blockDim.x;
  for (; i < total; i += stride)
    out[i] *= (i < bk) ? f1 : f2;
}

// ---------------------------------------------------------------------------
extern "C" void kernel_launch(void* const* d_in, const int* in_sizes, int n_in,
                              void* d_out, int out_size, void* d_ws, size_t ws_size,
                              hipStream_t stream)
{
  const float* v1   = (const float*)d_in[0];
  const float* v2   = (const float*)d_in[1];
  const int*   y    = (const int*)d_in[2];
  const int*   idx  = (const int*)d_in[3];
  const float* mem1 = (const float*)d_in[4];
  const float* mem2 = (const float*)d_in[5];
  float*  out  = (float*)d_out;
  double* sums = (double*)d_ws;

  hipMemsetAsync(d_ws, 0, 2 * sizeof(double), stream);

  nce_dots_kernel<<<B * CHUNKS, 256, 0, stream>>>(v1, v2, idx, mem1, mem2, out, sums);

  copy_mem_kernel<<<2048, 256, 0, stream>>>(
      (const float4*)mem1, (float4*)(out + OUT_M1),
      (const float4*)mem2, (float4*)(out + OUT_M2),
      (size_t)NROWS * D / 4);

  update_rows_kernel<<<B, 64, 0, stream>>>(v1, v2, y, mem1, mem2, out);

  scale_out_kernel<<<1024, 256, 0, stream>>>(out, sums);
}